// Round 11
// baseline (46.043 us; speedup 1.0000x reference)
//
#include <hip/hip_runtime.h>

#define COLS 8192
#define TPB  512

// LDS-only barrier: waits LDS ops, lets global stores stay in flight.
__device__ __forceinline__ void bar_lds() {
    asm volatile("s_waitcnt lgkmcnt(0)" ::: "memory");
    __builtin_amdgcn_sched_barrier(0);
    __builtin_amdgcn_s_barrier();
    __builtin_amdgcn_sched_barrier(0);
}
// In-wave LDS write->read ordering (no block barrier).
__device__ __forceinline__ void wait_lds() {
    asm volatile("s_waitcnt lgkmcnt(0)" ::: "memory");
    __builtin_amdgcn_sched_barrier(0);
}

// Register lane-blocked analysis level: lane l holds a[CIN*l .. CIN*l+CIN).
// d[i]=h3*a[2i]-h2*a[2i-1]+h1*a[2i-2]-h0*a[2i-3]; a'[i]=h0..h3 dot a[2i..2i-3].
#define ANA_LEVEL(CIN, ain, aout, dout, F0, F1, F2, F3)                       \
    {                                                                         \
        const int _src = (l - 1) & 63;                                        \
        const float _m1 = __shfl(ain[(CIN)-1], _src);                         \
        const float _m2 = __shfl(ain[(CIN)-2], _src);                         \
        const float _m3 = __shfl(ain[(CIN)-3], _src);                         \
        dout[0] = (F3)*ain[0] - (F2)*_m1 + (F1)*_m2 - (F0)*_m3;               \
        aout[0] = (F0)*ain[0] + (F1)*_m1 + (F2)*_m2 + (F3)*_m3;               \
        dout[1] = (F3)*ain[2] - (F2)*ain[1] + (F1)*ain[0] - (F0)*_m1;         \
        aout[1] = (F0)*ain[2] + (F1)*ain[1] + (F2)*ain[0] + (F3)*_m1;         \
        _Pragma("unroll")                                                     \
        for (int _j = 2; _j < (CIN)/2; ++_j) {                                \
            dout[_j] = (F3)*ain[2*_j] - (F2)*ain[2*_j-1] + (F1)*ain[2*_j-2] - (F0)*ain[2*_j-3]; \
            aout[_j] = (F0)*ain[2*_j] + (F1)*ain[2*_j-1] + (F2)*ain[2*_j-2] + (F3)*ain[2*_j-3]; \
        }                                                                     \
    }

// Register lane-blocked synthesis level (full-vector, circular across wave):
// rec[2j]=h3*d[j]+h1*d[j+1]+h0*a[j]+h2*a[j+1];
// rec[2j+1]=-h2*d[j+1]-h0*d[j+2]+h1*a[j+1]+h3*a[j+2]
#define SYN_LEVEL(CD, din, ain, rout, F0, F1, F2, F3)                         \
    {                                                                         \
        const int _src = (l + 1) & 63;                                        \
        const float _d0 = __shfl(din[0], _src);                               \
        const float _d1 = __shfl(din[1], _src);                               \
        const float _a0 = __shfl(ain[0], _src);                               \
        const float _a1 = __shfl(ain[1], _src);                               \
        _Pragma("unroll")                                                     \
        for (int _j = 0; _j < (CD); ++_j) {                                   \
            const float dj  = din[_j];                                        \
            const float dj1 = (_j+1 < (CD)) ? din[_j+1] : _d0;                \
            const float dj2 = (_j+2 < (CD)) ? din[_j+2] : ((_j+1 < (CD)) ? _d0 : _d1); \
            const float aj  = ain[_j];                                        \
            const float aj1 = (_j+1 < (CD)) ? ain[_j+1] : _a0;                \
            const float aj2 = (_j+2 < (CD)) ? ain[_j+2] : ((_j+1 < (CD)) ? _a0 : _a1); \
            rout[2*_j]   = (F3)*dj + (F1)*dj1 + (F0)*aj + (F2)*aj1;           \
            rout[2*_j+1] = -(F2)*dj1 - (F0)*dj2 + (F1)*aj1 + (F3)*aj2;        \
        }                                                                     \
    }

// One block per row. P0..P3: analysis lev0..3 (4 barriers, HBM-busy).
// Then ONE full sync, then a barrier-free stretch: every wave redundantly
// computes the tail (lev4..7 + synth7..4) in registers/shuffles, publishes
// rec4 to LDS (identical-value writes), and synthesizes its own 1/8 slice of
// rec3..rec0 in registers (halos computed redundantly). Waves drift freely.
__global__ __launch_bounds__(TPB) void despawn_kernel(
    const float* __restrict__ x, const float* __restrict__ scaling,
    float* __restrict__ out, int rows)
{
    __shared__ __align__(16) float B[4096];   // 16 KB  a0 / a2
    __shared__ __align__(16) float C[2048];   // 8 KB   a1 / a3[0..512) + rec4[512..1024)
    __shared__ __align__(16) float D[1536];   // 6 KB   d2[0..1024) | d3[1024..1536)

    const int row = blockIdx.x;
    const int tid = threadIdx.x;

    const float* __restrict__ xg       = x + (size_t)row * COLS;
    float* __restrict__       out_rec  = out + (size_t)row * COLS;
    float* __restrict__       out_coef = out + (size_t)rows * COLS + (size_t)row * COLS;

    // ---------------- P0: analysis level 0 (global float4) ----------------
    {
        const float h0 = scaling[0], h1 = scaling[1], h2 = scaling[2], h3 = scaling[3];
        const float g0 = h3, g1 = -h2, g2 = h1, g3 = -h0;
        const float4* __restrict__ xg4 = reinterpret_cast<const float4*>(xg);
        const int q8 = COLS / 8, qm = COLS / 4 - 1;
        for (int i = tid; i < q8; i += TPB) {
            const float4 va = xg4[(2 * i - 1) & qm];
            const float4 vb = xg4[2 * i];
            const float4 vc = xg4[2 * i + 1];
            float4 dv, av;
            dv.x = g0*vb.x + g1*va.w + g2*va.z + g3*va.y;
            av.x = h0*vb.x + h1*va.w + h2*va.z + h3*va.y;
            dv.y = g0*vb.z + g1*vb.y + g2*vb.x + g3*va.w;
            av.y = h0*vb.z + h1*vb.y + h2*vb.x + h3*va.w;
            dv.z = g0*vc.x + g1*vb.w + g2*vb.z + g3*vb.y;
            av.z = h0*vc.x + h1*vb.w + h2*vb.z + h3*vb.y;
            dv.w = g0*vc.z + g1*vc.y + g2*vc.x + g3*vb.w;
            av.w = h0*vc.z + h1*vc.y + h2*vc.x + h3*vb.w;
            reinterpret_cast<float4*>(out_coef)[i] = dv;   // stays in flight
            reinterpret_cast<float4*>(B)[i]        = av;
        }
        bar_lds();
    }

    // ---------------- P1..P3: analysis levels 1..3 (LDS float4) -----------
    {
        int n = COLS / 2, coff = COLS / 2, dOff = 0;
        float* cur = B;
        float* nxt = C;
        for (int lev = 1; lev <= 3; ++lev) {
            const float h0 = scaling[4*lev+0], h1 = scaling[4*lev+1],
                        h2 = scaling[4*lev+2], h3 = scaling[4*lev+3];
            const float g0 = h3, g1 = -h2, g2 = h1, g3 = -h0;
            const int half = n >> 1, qq = half >> 2, qm = (n >> 2) - 1;
            const float4* c4 = reinterpret_cast<const float4*>(cur);
            float4* o4 = reinterpret_cast<float4*>(out_coef + coff);
            float4* n4 = reinterpret_cast<float4*>(nxt);
            float4* D4 = reinterpret_cast<float4*>(D + dOff);
            const bool toD = (lev >= 2);
            for (int p = tid; p < qq; p += TPB) {
                const float4 va = c4[(2 * p - 1) & qm];
                const float4 vb = c4[2 * p];
                const float4 vc = c4[2 * p + 1];
                float4 dv, av;
                dv.x = g0*vb.x + g1*va.w + g2*va.z + g3*va.y;
                av.x = h0*vb.x + h1*va.w + h2*va.z + h3*va.y;
                dv.y = g0*vb.z + g1*vb.y + g2*vb.x + g3*va.w;
                av.y = h0*vb.z + h1*vb.y + h2*vb.x + h3*va.w;
                dv.z = g0*vc.x + g1*vb.w + g2*vb.z + g3*vb.y;
                av.z = h0*vc.x + h1*vb.w + h2*vb.z + h3*vb.y;
                dv.w = g0*vc.z + g1*vc.y + g2*vc.x + g3*vb.w;
                av.w = h0*vc.z + h1*vc.y + h2*vc.x + h3*vb.w;
                o4[p] = dv;
                n4[p] = av;
                if (toD) D4[p] = dv;
            }
            if (lev == 3) __syncthreads();   // only full (vmcnt) drain
            else          bar_lds();
            coff += half;
            if (toD) dOff += half;
            n = half;
            float* t = cur; cur = nxt; nxt = t;
        }
    }
    // a3 in C[0..512), d2 in D[0..1024), d3 in D[1024..1536). NO MORE BARRIERS.

    const int w = tid >> 6;   // wave 0..7
    const int l = tid & 63;   // lane

    // ---------------- redundant register tail (every wave) ----------------
    float a3r[8];
    {
        const float4 v0 = reinterpret_cast<const float4*>(C)[2*l];
        const float4 v1 = reinterpret_cast<const float4*>(C)[2*l+1];
        a3r[0]=v0.x; a3r[1]=v0.y; a3r[2]=v0.z; a3r[3]=v0.w;
        a3r[4]=v1.x; a3r[5]=v1.y; a3r[6]=v1.z; a3r[7]=v1.w;
    }
    float a4r[4], d4r[4];
    ANA_LEVEL(8, a3r, a4r, d4r, scaling[16], scaling[17], scaling[18], scaling[19]);
    float a5r[2], d5r[2];
    ANA_LEVEL(4, a4r, a5r, d5r, scaling[20], scaling[21], scaling[22], scaling[23]);
    float a6r, d6r;
    {   // lev6 (CIN=2 special): a5 2/lane -> d6,a6 1/lane
        const float F0=scaling[24],F1=scaling[25],F2=scaling[26],F3=scaling[27];
        const int s1 = (l-1)&63, s2 = (l-2)&63;
        const float x0 = a5r[0];
        const float x1 = __shfl(a5r[1], s1);
        const float x2 = __shfl(a5r[0], s1);
        const float x3 = __shfl(a5r[1], s2);
        d6r = F3*x0 - F2*x1 + F1*x2 - F0*x3;
        a6r = F0*x0 + F1*x1 + F2*x2 + F3*x3;
    }
    float d7r, apr;
    {   // lev7 (full-shuffle): a6 1/lane -> d7,ap at lanes<32
        const float F0=scaling[28],F1=scaling[29],F2=scaling[30],F3=scaling[31];
        const int i2 = 2*l;
        const float x0 = __shfl(a6r, i2 & 63);
        const float x1 = __shfl(a6r, (i2-1)&63);
        const float x2 = __shfl(a6r, (i2-2)&63);
        const float x3 = __shfl(a6r, (i2-3)&63);
        d7r = F3*x0 - F2*x1 + F1*x2 - F0*x3;
        apr = F0*x0 + F1*x1 + F2*x2 + F3*x3;
    }
    if (w == 0) {   // tail coefficient writes (once)
        reinterpret_cast<float4*>(out_coef + 7680)[l] = make_float4(d4r[0],d4r[1],d4r[2],d4r[3]);
        reinterpret_cast<float2*>(out_coef + 7936)[l] = make_float2(d5r[0],d5r[1]);
        out_coef[8064 + l] = d6r;
        if (l < 32) { out_coef[8128 + l] = d7r; out_coef[8160 + l] = apr; }
    }
    float rec7;
    {   // synth7: pairs at lane j<32, then redistribute to 1/lane
        const float F0=scaling[28],F1=scaling[29],F2=scaling[30],F3=scaling[31];
        const float dj = d7r, dj1 = __shfl(d7r,(l+1)&31), dj2 = __shfl(d7r,(l+2)&31);
        const float aj = apr, aj1 = __shfl(apr,(l+1)&31), aj2 = __shfl(apr,(l+2)&31);
        const float r0 = F3*dj + F1*dj1 + F0*aj + F2*aj1;
        const float r1 = -F2*dj1 - F0*dj2 + F1*aj1 + F3*aj2;
        const float e0 = __shfl(r0, l>>1);
        const float e1 = __shfl(r1, l>>1);
        rec7 = (l & 1) ? e1 : e0;
    }
    float rec6[2];
    {   // synth6: d6,rec7 1/lane -> rec6 2/lane
        const float F0=scaling[24],F1=scaling[25],F2=scaling[26],F3=scaling[27];
        const float dj = d6r, dj1 = __shfl(d6r,(l+1)&63), dj2 = __shfl(d6r,(l+2)&63);
        const float aj = rec7, aj1 = __shfl(rec7,(l+1)&63), aj2 = __shfl(rec7,(l+2)&63);
        rec6[0] = F3*dj + F1*dj1 + F0*aj + F2*aj1;
        rec6[1] = -F2*dj1 - F0*dj2 + F1*aj1 + F3*aj2;
    }
    float rec5[4];
    SYN_LEVEL(2, d5r, rec6, rec5, scaling[20], scaling[21], scaling[22], scaling[23]);
    float rec4r[8];
    SYN_LEVEL(4, d4r, rec5, rec4r, scaling[16], scaling[17], scaling[18], scaling[19]);
    // publish rec4 (identical values from every wave; each wave writes all 512)
    reinterpret_cast<float4*>(C + 512)[2*l]   = make_float4(rec4r[0],rec4r[1],rec4r[2],rec4r[3]);
    reinterpret_cast<float4*>(C + 512)[2*l+1] = make_float4(rec4r[4],rec4r[5],rec4r[6],rec4r[7]);
    wait_lds();

    // ---------------- per-wave slice synthesis (barrier-free) -------------
    // synth3: rec3[128w+2l..+1] (2/lane) + halo r3h[4]=rec3[128(w+1)+0..3]
    float rec3[2], r3h[4];
    {
        const float F0=scaling[12],F1=scaling[13],F2=scaling[14],F3=scaling[15];
        const int j = 64*w + l;
        const float a0v = C[512 + (j & 511)];
        const float a1v = C[512 + ((j+1) & 511)];
        const float a2v = C[512 + ((j+2) & 511)];
        const float e0  = D[1024 + (j & 511)];
        const float e1  = D[1024 + ((j+1) & 511)];
        const float e2  = D[1024 + ((j+2) & 511)];
        rec3[0] = F3*e0 + F1*e1 + F0*a0v + F2*a1v;
        rec3[1] = -F2*e1 - F0*e2 + F1*a1v + F3*a2v;
        #pragma unroll
        for (int q = 0; q < 2; ++q) {
            const int jh = 64*(w+1) + q;
            const float A0 = C[512 + (jh & 511)];
            const float A1 = C[512 + ((jh+1) & 511)];
            const float A2 = C[512 + ((jh+2) & 511)];
            const float E0 = D[1024 + (jh & 511)];
            const float E1 = D[1024 + ((jh+1) & 511)];
            const float E2 = D[1024 + ((jh+2) & 511)];
            r3h[2*q]   = F3*E0 + F1*E1 + F0*A0 + F2*A1;
            r3h[2*q+1] = -F2*E1 - F0*E2 + F1*A1 + F3*A2;
        }
    }
    // synth2: rec2[256w+4l..+3] (4/lane) + halo r2h[3]=rec2[256(w+1)+0..2]
    float rec2[4], r2h[3];
    {
        const float F0=scaling[8],F1=scaling[9],F2=scaling[10],F3=scaling[11];
        const int lp1 = (l+1)&63;
        const float n0 = __shfl(rec3[0], lp1);
        const float n1 = __shfl(rec3[1], lp1);
        const float b2 = (l==63) ? r3h[0] : n0;   // rec3[128w+2l+2]
        const float b3 = (l==63) ? r3h[1] : n1;   // rec3[128w+2l+3]
        const int jj = 128*w + 2*l;
        const float e0 = D[jj & 1023], e1 = D[(jj+1)&1023],
                    e2 = D[(jj+2)&1023], e3 = D[(jj+3)&1023];
        rec2[0] = F3*e0 + F1*e1 + F0*rec3[0] + F2*rec3[1];
        rec2[1] = -F2*e1 - F0*e2 + F1*rec3[1] + F3*b2;
        rec2[2] = F3*e1 + F1*e2 + F0*rec3[1] + F2*b2;
        rec2[3] = -F2*e2 - F0*e3 + F1*b2 + F3*b3;
        const int jh = 128*(w+1);
        const float E0 = D[jh & 1023], E1 = D[(jh+1)&1023], E2 = D[(jh+2)&1023];
        r2h[0] = F3*E0 + F1*E1 + F0*r3h[0] + F2*r3h[1];
        r2h[1] = -F2*E1 - F0*E2 + F1*r3h[1] + F3*r3h[2];
        r2h[2] = F3*E1 + F1*E2 + F0*r3h[1] + F2*r3h[2];
    }
    // synth1: rec1[512w+8l..+7] (8/lane) + halo r1h[2]; d1 from global (L2)
    float rec1[8], r1h[2];
    {
        const float F0=scaling[4],F1=scaling[5],F2=scaling[6],F3=scaling[7];
        const float* __restrict__ d1g = out_coef + 4096;
        const int jb = 256*w + 4*l;
        float dw[6];
        {
            const float4 v = *reinterpret_cast<const float4*>(d1g + jb);
            dw[0]=v.x; dw[1]=v.y; dw[2]=v.z; dw[3]=v.w;
            const float2 v2 = *reinterpret_cast<const float2*>(d1g + ((jb+4)&2047));
            dw[4]=v2.x; dw[5]=v2.y;
        }
        const int lp1 = (l+1)&63;
        const float n0 = __shfl(rec2[0], lp1);
        const float n1 = __shfl(rec2[1], lp1);
        const float A4 = (l==63) ? r2h[0] : n0;
        const float A5 = (l==63) ? r2h[1] : n1;
        const float A[6] = {rec2[0],rec2[1],rec2[2],rec2[3],A4,A5};
        #pragma unroll
        for (int p = 0; p < 4; ++p) {
            rec1[2*p]   = F3*dw[p] + F1*dw[p+1] + F0*A[p] + F2*A[p+1];
            rec1[2*p+1] = -F2*dw[p+1] - F0*dw[p+2] + F1*A[p+1] + F3*A[p+2];
        }
        const int jh = (256*(w+1)) & 2047;
        const float H0 = d1g[jh], H1 = d1g[(jh+1)&2047], H2 = d1g[(jh+2)&2047];
        r1h[0] = F3*H0 + F1*H1 + F0*r2h[0] + F2*r2h[1];
        r1h[1] = -F2*H1 - F0*H2 + F1*r2h[1] + F3*r2h[2];
    }
    // synth0: rec0[1024w+16l..+15] streamed; d0 from global (L2/L3)
    {
        const float F0=scaling[0],F1=scaling[1],F2=scaling[2],F3=scaling[3];
        const float* __restrict__ d0g = out_coef;
        const int jb = 512*w + 8*l;
        float dw[10];
        {
            const float4 v0 = *reinterpret_cast<const float4*>(d0g + jb);
            const float4 v1 = *reinterpret_cast<const float4*>(d0g + jb + 4);
            const float2 v2 = *reinterpret_cast<const float2*>(d0g + ((jb+8)&4095));
            dw[0]=v0.x; dw[1]=v0.y; dw[2]=v0.z; dw[3]=v0.w;
            dw[4]=v1.x; dw[5]=v1.y; dw[6]=v1.z; dw[7]=v1.w;
            dw[8]=v2.x; dw[9]=v2.y;
        }
        const int lp1 = (l+1)&63;
        const float n0 = __shfl(rec1[0], lp1);
        const float n1 = __shfl(rec1[1], lp1);
        const float A8 = (l==63) ? r1h[0] : n0;
        const float A9 = (l==63) ? r1h[1] : n1;
        const float A[10] = {rec1[0],rec1[1],rec1[2],rec1[3],rec1[4],rec1[5],rec1[6],rec1[7],A8,A9};
        float4* __restrict__ o4 = reinterpret_cast<float4*>(out_rec + 1024*w + 16*l);
        #pragma unroll
        for (int c = 0; c < 4; ++c) {
            float4 rv;
            rv.x = F3*dw[2*c]   + F1*dw[2*c+1] + F0*A[2*c]   + F2*A[2*c+1];
            rv.y = -F2*dw[2*c+1] - F0*dw[2*c+2] + F1*A[2*c+1] + F3*A[2*c+2];
            rv.z = F3*dw[2*c+1] + F1*dw[2*c+2] + F0*A[2*c+1] + F2*A[2*c+2];
            rv.w = -F2*dw[2*c+2] - F0*dw[2*c+3] + F1*A[2*c+2] + F3*A[2*c+3];
            o4[c] = rv;
        }
    }
}

extern "C" void kernel_launch(void* const* d_in, const int* in_sizes, int n_in,
                              void* d_out, int out_size, void* d_ws, size_t ws_size,
                              hipStream_t stream) {
    const float* x       = (const float*)d_in[0];
    const float* scaling = (const float*)d_in[1];
    float* out           = (float*)d_out;
    const int rows = in_sizes[0] / COLS;
    despawn_kernel<<<rows, TPB, 0, stream>>>(x, scaling, out, rows);
}

// Round 13
// 42.198 us; speedup vs baseline: 1.0911x; 1.0911x over previous
//
#include <hip/hip_runtime.h>

#define COLS   8192
#define LEVELS 8
#define TPB    512

typedef float f4_t __attribute__((ext_vector_type(4)));   // nt-store-compatible

__device__ __forceinline__ void nt_store4(float* p, const float4 v) {
    f4_t w; w.x = v.x; w.y = v.y; w.z = v.z; w.w = v.w;
    __builtin_nontemporal_store(w, reinterpret_cast<f4_t*>(p));
}

// LDS-only barrier: waits LDS ops, lets global (vmcnt) stores stay in flight
// across the phase chain. Full __syncthreads() is used once, after the wave-0
// tail, to drain coeff stores before synthesis re-reads them from global.
__device__ __forceinline__ void bar_lds() {
    asm volatile("s_waitcnt lgkmcnt(0)" ::: "memory");
    __builtin_amdgcn_sched_barrier(0);
    __builtin_amdgcn_s_barrier();
    __builtin_amdgcn_sched_barrier(0);
}

// One block per row. Proven 42.7us phase chain + NONTEMPORAL stores for all
// never-re-read streams (rec output, d2..d7 coeffs). d0/d1 stay cached: they
// are re-read in synth1/synth0 ~25us later, and with the nt streams out of
// the way the 128 resident rows' d0+d1 (3 MB/XCD) fit in the 4 MB L2.
__global__ __launch_bounds__(TPB, 8) void despawn_kernel(
    const float* __restrict__ x, const float* __restrict__ scaling,
    float* __restrict__ out, int rows)
{
    __shared__ __align__(16) float B[COLS / 2];   // 16 KB
    __shared__ __align__(16) float C[COLS / 4];   // 8 KB
    __shared__ __align__(16) float D[COLS / 4];   // 8 KB
    __shared__ float filt[LEVELS * 4];

    const int row = blockIdx.x;
    const int tid = threadIdx.x;

    if (tid < LEVELS * 4) filt[tid] = scaling[tid];
    bar_lds();

    const float* __restrict__ xg       = x + (size_t)row * COLS;
    float* __restrict__       out_rec  = out + (size_t)row * COLS;
    float* __restrict__       out_coef = out + (size_t)rows * COLS + (size_t)row * COLS;

    // ---------------- analysis level 0 (global float4, 4 outputs/thread) ----
    // d[k] = g0*x[2k] + g1*x[2k-1] + g2*x[2k-2] + g3*x[2k-3]   (mod 8192)
    {
        const float h0 = filt[0], h1 = filt[1], h2 = filt[2], h3 = filt[3];
        const float g0 = h3, g1 = -h2, g2 = h1, g3 = -h0;
        const float4* __restrict__ xg4 = reinterpret_cast<const float4*>(xg);
        const int q8 = COLS / 8, qm = COLS / 4 - 1;
        for (int i = tid; i < q8; i += TPB) {
            const float4 va = xg4[(2 * i - 1) & qm];   // x[8i-4..8i-1]
            const float4 vb = xg4[2 * i];              // x[8i  ..8i+3]
            const float4 vc = xg4[2 * i + 1];          // x[8i+4..8i+7]
            float4 dv, av;
            dv.x = g0*vb.x + g1*va.w + g2*va.z + g3*va.y;
            av.x = h0*vb.x + h1*va.w + h2*va.z + h3*va.y;
            dv.y = g0*vb.z + g1*vb.y + g2*vb.x + g3*va.w;
            av.y = h0*vb.z + h1*vb.y + h2*vb.x + h3*va.w;
            dv.z = g0*vc.x + g1*vb.w + g2*vb.z + g3*vb.y;
            av.z = h0*vc.x + h1*vb.w + h2*vb.z + h3*vb.y;
            dv.w = g0*vc.z + g1*vc.y + g2*vc.x + g3*vb.w;
            av.w = h0*vc.z + h1*vc.y + h2*vc.x + h3*vb.w;
            reinterpret_cast<float4*>(out_coef)[i] = dv;   // d0: CACHED (re-read)
            reinterpret_cast<float4*>(B)[i]        = av;
        }
        bar_lds();
    }

    // ---------------- analysis levels 1..3 (LDS float4, 4 outputs/thread) ---
    int n = COLS / 2, coff = COLS / 2, dOff = 0;
    float* cur = B;
    float* nxt = C;
    for (int lev = 1; lev <= 3; ++lev) {
        const float h0 = filt[4*lev+0], h1 = filt[4*lev+1],
                    h2 = filt[4*lev+2], h3 = filt[4*lev+3];
        const float g0 = h3, g1 = -h2, g2 = h1, g3 = -h0;
        const int half = n >> 1, qq = half >> 2, qm = (n >> 2) - 1;
        const float4* c4 = reinterpret_cast<const float4*>(cur);
        float* ob = out_coef + coff;
        float4* n4 = reinterpret_cast<float4*>(nxt);
        float4* D4 = reinterpret_cast<float4*>(D + dOff);
        const bool toD = (lev >= 2);
        for (int p = tid; p < qq; p += TPB) {
            const float4 va = c4[(2 * p - 1) & qm];
            const float4 vb = c4[2 * p];
            const float4 vc = c4[2 * p + 1];
            float4 dv, av;
            dv.x = g0*vb.x + g1*va.w + g2*va.z + g3*va.y;
            av.x = h0*vb.x + h1*va.w + h2*va.z + h3*va.y;
            dv.y = g0*vb.z + g1*vb.y + g2*vb.x + g3*va.w;
            av.y = h0*vb.z + h1*vb.y + h2*vb.x + h3*va.w;
            dv.z = g0*vc.x + g1*vb.w + g2*vb.z + g3*vb.y;
            av.z = h0*vc.x + h1*vb.w + h2*vb.z + h3*vb.y;
            dv.w = g0*vc.z + g1*vc.y + g2*vc.x + g3*vb.w;
            av.w = h0*vc.z + h1*vc.y + h2*vc.x + h3*vb.w;
            if (toD) {
                nt_store4(ob + 4*p, dv);   // d2/d3: never re-read from global
                D4[p] = dv;                // re-read comes from LDS
            } else {
                reinterpret_cast<float4*>(ob)[p] = dv;   // d1: CACHED (re-read)
            }
            n4[p] = av;
        }
        bar_lds();
        coff += half;
        if (toD) dOff += half;
        n = half;
        float* t = cur; cur = nxt; nxt = t;
    }
    // approx(512) now in C (cur == C)

    // ---------------- wave-0 tail: levels 4..7 both directions --------------
    // D layout: lev2@0(1024) lev3@1024(512) lev4@1536(256) lev5@1792(128)
    //           lev6@1920(64) lev7@1984(32) approx@2016(32)
    if (tid < 64) {
        float* acur = C;
        float* anxt = B;
        int nn = 512, coffW = 7680, dW = 1536;
        for (int lev = 4; lev <= 7; ++lev) {
            const float h0 = filt[4*lev+0], h1 = filt[4*lev+1],
                        h2 = filt[4*lev+2], h3 = filt[4*lev+3];
            const float g0 = h3, g1 = -h2, g2 = h1, g3 = -h0;
            const int half = nn >> 1, mask = nn - 1;
            for (int i = tid; i < half; i += 64) {
                const int b = 2 * i;
                const float x0 = acur[b];
                const float x1 = acur[(b - 1) & mask];
                const float x2 = acur[(b - 2) & mask];
                const float x3 = acur[(b - 3) & mask];
                const float d = g0*x0 + g1*x1 + g2*x2 + g3*x3;
                const float a = h0*x0 + h1*x1 + h2*x2 + h3*x3;
                D[dW + i] = d;
                __builtin_nontemporal_store(d, &out_coef[coffW + i]);  // never re-read
                if (lev == 7) {
                    D[2016 + i] = a;
                    __builtin_nontemporal_store(a, &out_coef[8160 + i]);
                }
                else          anxt[i] = a;
            }
            __builtin_amdgcn_wave_barrier();
            coffW += half; dW += half; nn = half;
            float* t = acur; acur = anxt; anxt = t;
        }
        // synthesis lev7..4 (in-wave)
        int mS = 32, dS = 1984;
        const float* aprevW = D + 2016;
        for (int lev = 7; lev >= 4; --lev) {
            const float h0 = filt[4*lev+0], h1 = filt[4*lev+1],
                        h2 = filt[4*lev+2], h3 = filt[4*lev+3];
            const float g0 = h3, g1 = -h2, g2 = h1, g3 = -h0;
            const int mm = mS - 1;
            float* recW = (lev & 1) ? B : C;
            for (int j = tid; j < mS; j += 64) {
                const float dj  = D[dS + j];
                const float dj1 = D[dS + ((j + 1) & mm)];
                const float dj2 = D[dS + ((j + 2) & mm)];
                const float aj  = aprevW[j];
                const float aj1 = aprevW[(j + 1) & mm];
                const float aj2 = aprevW[(j + 2) & mm];
                recW[2*j]     = g0*dj  + g2*dj1 + h0*aj  + h2*aj1;
                recW[2*j + 1] = g1*dj1 + g3*dj2 + h1*aj1 + h3*aj2;
            }
            __builtin_amdgcn_wave_barrier();
            aprevW = recW; mS <<= 1; dS -= mS;
        }
    }
    __syncthreads();   // FULL drain: d0/d1 stores must be visible before re-read
    // lev4 rec (512) now in C

    // ---------------- synthesis levels 3..0 (all threads, 4 out/thread) -----
    // rec[2j]   = g0*d[j]   + g2*d[j+1] + h0*a[j]   + h2*a[j+1]
    // rec[2j+1] = g1*d[j+1] + g3*d[j+2] + h1*a[j+1] + h3*a[j+2]   (mod m)
#define SYNTH_BODY(d2)                                                        \
    for (int p = tid; p < mp; p += TPB) {                                     \
        const float2 dv0 = (d2)[p];                                           \
        const float2 dv1 = (d2)[(p + 1) & mm];                                \
        const float2 av0 = a2[p];                                             \
        const float2 av1 = a2[(p + 1) & mm];                                  \
        const float r0 = g0*dv0.x + g2*dv0.y + h0*av0.x + h2*av0.y;           \
        const float r1 = g1*dv0.y + g3*dv1.x + h1*av0.y + h3*av1.x;           \
        const float r2 = g0*dv0.y + g2*dv1.x + h0*av0.y + h2*av1.x;           \
        const float r3 = g1*dv1.x + g3*dv1.y + h1*av1.x + h3*av1.y;           \
        const float4 rv = make_float4(r0, r1, r2, r3);                        \
        if (last) nt_store4(out_rec + 4*p, rv);                               \
        else      reinterpret_cast<float4*>(rec)[p] = rv;                     \
    }

    const float* aprev = C;
    int m = 512;
    for (int lev = 3; lev >= 0; --lev) {
        const float h0 = filt[4*lev+0], h1 = filt[4*lev+1],
                    h2 = filt[4*lev+2], h3 = filt[4*lev+3];
        const float g0 = h3, g1 = -h2, g2 = h1, g3 = -h0;
        const int mp = m >> 1, mm = mp - 1;
        const float2* a2 = reinterpret_cast<const float2*>(aprev);
        float* rec = (lev & 1) ? B : C;   // lev3->B lev2->C lev1->B
        const bool last = (lev == 0);
        if (lev >= 2) {
            const float2* dL = reinterpret_cast<const float2*>(D + ((lev == 3) ? 1024 : 0));
            SYNTH_BODY(dL)
        } else {
            const float2* __restrict__ dG =
                reinterpret_cast<const float2*>(out_coef + ((lev == 1) ? 4096 : 0));
            SYNTH_BODY(dG)
        }
        if (lev) bar_lds();
        aprev = rec; m <<= 1;
    }
#undef SYNTH_BODY
}

extern "C" void kernel_launch(void* const* d_in, const int* in_sizes, int n_in,
                              void* d_out, int out_size, void* d_ws, size_t ws_size,
                              hipStream_t stream) {
    const float* x       = (const float*)d_in[0];
    const float* scaling = (const float*)d_in[1];
    float* out           = (float*)d_out;
    const int rows = in_sizes[0] / COLS;
    despawn_kernel<<<rows, TPB, 0, stream>>>(x, scaling, out, rows);
}